// Round 17
// baseline (171.309 us; speedup 1.0000x reference)
//
#include <hip/hip_runtime.h>
#include <hip/hip_bf16.h>

#define NNODES 100000
#define NEDGES 1600000
#define NBUCK 391        // ceil(NNODES / 256), 256 nodes per bucket
#define BUCK_SHIFT 8
#define BCAP 5120        // fixed bucket capacity (mean 4092, +16 sigma)
#define NBLK_A 782       // ceil(NEDGES / 2048)
#define GEMM_BLOCKS 1563 // ceil(NNODES / 64)

typedef short short8 __attribute__((ext_vector_type(8)));
typedef float floatx4 __attribute__((ext_vector_type(4)));
typedef float floatx2 __attribute__((ext_vector_type(2)));

__device__ inline float bf2f_lo(unsigned int v) {
  union { unsigned int i; float f; } u; u.i = v << 16; return u.f;
}
__device__ inline float bf2f_hi(unsigned int v) {
  union { unsigned int i; float f; } u; u.i = v & 0xffff0000u; return u.f;
}
__device__ inline unsigned short f2bf(float f) {  // RNE
  union { float f; unsigned int i; } u; u.f = f;
  unsigned int r = u.i + 0x7fffu + ((u.i >> 16) & 1u);
  return (unsigned short)(r >> 16);
}

// ---------------------------------------------------------------------------
// Weight prep body: Bcat = [Wl | Wr] (128 x 2*half) -> bf16 fragment-
// contiguous layout for the GEMM's B-panel register loads.
// ---------------------------------------------------------------------------
__device__ void prep_body(int bid, int nblk, const float* __restrict__ Wl,
                          const float* __restrict__ Wr,
                          short* __restrict__ Bswz, int half) {
  int total = 128 * 2 * half;
  int stride = nblk * 256;
  for (int i = bid * 256 + threadIdx.x; i < total; i += stride) {
    int j = i & 7;
    int lane = (i >> 3) & 63;
    int f = i >> 9;  // frag id = ct*4 + ks
    int ks = f & 3, ct = f >> 2;
    int k = ks * 32 + ((lane >> 4) << 3) + j;
    int c = ct * 16 + (lane & 15);
    float v = (c < half) ? Wl[k * half + c] : Wr[k * half + (c - half)];
    Bswz[i] = (short)f2bf(v);
  }
}

// ---------------------------------------------------------------------------
// GEMM1 body (512 threads / 8 waves): [y1(fp8)|r1(bf16)] = x(fp32)@[W1l|W1r].
// R14-proven: LDS A staging, CT=2 (32 AGPRs/wave, occupancy ~51%).
// ---------------------------------------------------------------------------
__device__ void gemm1_body(int bid, const float* __restrict__ A,
                           const short* __restrict__ Bswz,
                           unsigned char* __restrict__ y8,
                           unsigned short* __restrict__ r1, int nrows,
                           char* smem) {
  constexpr int PW = 32, CT = 2;
  auto At = (unsigned short (*)[136])smem;

  const int tid = threadIdx.x;
  const int lane = tid & 63;
  const int wave = tid >> 6;  // 0..7
  const int row0 = bid * 64;

  for (int i = tid; i < 64 * 32; i += 512) {
    int r = i >> 5, c4 = (i & 31) << 2;
    int gr = row0 + r;
    float4 v = make_float4(0.f, 0.f, 0.f, 0.f);
    if (gr < nrows) v = *(const float4*)(A + (size_t)gr * 128 + c4);
    ushort4 u = make_ushort4(f2bf(v.x), f2bf(v.y), f2bf(v.z), f2bf(v.w));
    *(ushort4*)&At[r][c4] = u;
  }
  __syncthreads();

  short8 bfrag[CT][4];
#pragma unroll
  for (int ct = 0; ct < CT; ++ct)
#pragma unroll
    for (int ks = 0; ks < 4; ++ks)
      bfrag[ct][ks] =
          *(const short8*)(Bswz + ((((wave * CT + ct) * 4 + ks) * 64 + lane) << 3));

  floatx4 acc[4][CT];
#pragma unroll
  for (int rt = 0; rt < 4; ++rt)
#pragma unroll
    for (int ct = 0; ct < CT; ++ct) acc[rt][ct] = (floatx4)(0.f);

#pragma unroll
  for (int rt = 0; rt < 4; ++rt) {
#pragma unroll
    for (int ks = 0; ks < 4; ++ks) {
      short8 af = *(const short8*)&At[rt * 16 + (lane & 15)][ks * 32 + ((lane >> 4) << 3)];
#pragma unroll
      for (int ct = 0; ct < CT; ++ct)
        acc[rt][ct] = __builtin_amdgcn_mfma_f32_16x16x32_bf16(
            bfrag[ct][ks], af, acc[rt][ct], 0, 0, 0);
    }
  }
  __syncthreads();  // A-reads done; reuse smem for C staging

  // Staging: Cs8 = 32 rows x 144B (fp8), Cs16 = 32 rows x 136 ushorts.
  unsigned char* Cs8 = (unsigned char*)smem;
  unsigned short* Cs16 = (unsigned short*)(smem + 32 * 144);

#pragma unroll
  for (int p = 0; p < 2; ++p) {  // 2 passes of 32 rows
    if (p) __syncthreads();
#pragma unroll
    for (int rr = 0; rr < 2; ++rr) {
      int rt = p * 2 + rr;
      int rl = rr * 16 + (lane & 15);
#pragma unroll
      for (int ct = 0; ct < CT; ++ct) {
        int c = wave * PW + ct * 16 + ((lane >> 4) << 2);
        floatx4 a = acc[rt][ct];
        if (c < 128) {  // wave-uniform (waves 0-3)
          int pk = __builtin_amdgcn_cvt_pk_fp8_f32(a[0], a[1], 0, false);
          pk = __builtin_amdgcn_cvt_pk_fp8_f32(a[2], a[3], pk, true);
          *(unsigned int*)(Cs8 + rl * 144 + c) = (unsigned int)pk;
        } else {
          ushort4 u = make_ushort4(f2bf(a[0]), f2bf(a[1]), f2bf(a[2]), f2bf(a[3]));
          *(ushort4*)(Cs16 + rl * 136 + (c - 128)) = u;
        }
      }
    }
    __syncthreads();
    // y1 fp8 writeback: 32 rows x 8 uint4 chunks = 256.
    if (tid < 256) {
      int rl = tid >> 3, cpos = (tid & 7) << 4;
      int gr = row0 + p * 32 + rl;
      if (gr < nrows) {
        uint4 v = *(const uint4*)(Cs8 + rl * 144 + cpos);
        *(uint4*)(y8 + (size_t)gr * 128 + cpos) = v;
      }
    }
    // r1 bf16 writeback: 32 rows x 16 uint4 chunks = 512 (1/thread).
    {
      int rl = tid >> 4, cpos = (tid & 15) << 3;
      int gr = row0 + p * 32 + rl;
      if (gr < nrows) {
        uint4 v = *(const uint4*)(Cs16 + rl * 136 + cpos);
        *(uint4*)(r1 + (size_t)gr * 128 + cpos) = v;
      }
    }
  }
}

// ---------------------------------------------------------------------------
// CSR build: fixed-capacity buckets (base = b*BCAP) — no count/scan kernels.
// ---------------------------------------------------------------------------
__device__ void partition_body(int bid, const int* __restrict__ ei,
                               int* __restrict__ bcur,
                               unsigned int* __restrict__ part, char* smem) {
  int* h = (int*)smem;          // NBUCK
  int* r = h + NBUCK;           // NBUCK
  for (int i = threadIdx.x; i < NBUCK; i += blockDim.x) { h[i] = 0; r[i] = 0; }
  __syncthreads();
  int e0 = bid * 2048;
  int eend = min(e0 + 2048, NEDGES);
  for (int e = e0 + threadIdx.x; e < eend; e += blockDim.x)
    atomicAdd(&h[ei[NEDGES + e] >> BUCK_SHIFT], 1);
  __syncthreads();
  for (int i = threadIdx.x; i < NBUCK; i += blockDim.x) {
    int c = h[i];
    h[i] = c ? atomicAdd(&bcur[i], c) : 0;  // reserve chunk
  }
  __syncthreads();
  for (int e = e0 + threadIdx.x; e < eend; e += blockDim.x) {
    int s = ei[e], d = ei[NEDGES + e];
    int b = d >> BUCK_SHIFT;
    int pos = h[b] + atomicAdd(&r[b], 1);
    if (pos < (b + 1) * BCAP)  // overflow guard (never fires: cap = +16 sigma)
      part[pos] = (unsigned int)s | ((unsigned int)(d & 255) << 24);
  }
}

// front1 = prep_b W1 (128) || prep_b W2 (64) || bcur init (1)
__global__ __launch_bounds__(256) void front1(
    const float* __restrict__ W1l, const float* __restrict__ W1r,
    short* __restrict__ bswz1, const float* __restrict__ W2l,
    const float* __restrict__ W2r, short* __restrict__ bswz2,
    int* __restrict__ bcur) {
  int bid = blockIdx.x;
  if (bid < 128) {
    prep_body(bid, 128, W1l, W1r, bswz1, 128);
  } else if (bid < 192) {
    prep_body(bid - 128, 64, W2l, W2r, bswz2, 64);
  } else {
    for (int i = threadIdx.x; i < NBUCK; i += 256) bcur[i] = i * BCAP;
  }
}

// front2 = bucket_partition (782, dispatched FIRST so its low-ILP work
// overlaps the GEMM ramp instead of forming an idle tail) || GEMM1 (1563).
__global__ __launch_bounds__(512) void front2(
    const float* __restrict__ x, const short* __restrict__ bswz1,
    unsigned char* __restrict__ y8, unsigned short* __restrict__ r1b,
    const int* __restrict__ ei, int* __restrict__ bcur,
    unsigned int* __restrict__ part) {
  __shared__ char smem[17408];
  int bid = blockIdx.x;
  if (bid < NBLK_A) {
    partition_body(bid, ei, bcur, part, smem);
  } else {
    gemm1_body(bid - NBLK_A, x, bswz1, y8, r1b, NNODES, smem);
  }
}

// Per bucket: local 256-node hist -> rowptr (absolute) + rowdeg; place srcs
// into adj (writes confined to the bucket's own fixed region).
__global__ __launch_bounds__(256) void bucket_build(
    const unsigned int* __restrict__ part, const int* __restrict__ bcur,
    int* __restrict__ rowptr, int* __restrict__ rowdeg,
    int* __restrict__ adj) {
  __shared__ int h[256], ex[256];
  int b = blockIdx.x;
  int t = threadIdx.x;
  int base = b * BCAP;
  int cnt = min(bcur[b] - base, BCAP);
  int end = base + cnt;
  h[t] = 0;
  __syncthreads();
  for (int i = base + t; i < end; i += 256)
    atomicAdd(&h[part[i] >> 24], 1);
  __syncthreads();
  int v = h[t];
  int acc = v;
  ex[t] = acc;
  __syncthreads();
  for (int off = 1; off < 256; off <<= 1) {
    int add = (t >= off) ? ex[t - off] : 0;
    __syncthreads();
    acc += add;
    ex[t] = acc;
    __syncthreads();
  }
  int excl = acc - v;
  int node = (b << BUCK_SHIFT) + t;
  if (node < NNODES) {
    rowptr[node] = base + excl;
    rowdeg[node] = v;
  }
  h[t] = 0;
  ex[t] = excl;
  __syncthreads();
  for (int i = base + t; i < end; i += 256) {
    unsigned int p = part[i];
    int ld = p >> 24;
    int rank = atomicAdd(&h[ld], 1);
    adj[base + ex[ld] + rank] = (int)(p & 0xFFFFFFu);
  }
}

// ---------------------------------------------------------------------------
// Layer-1 gather + epilogue: h = relu(LN(mean_agg(y1_fp8) + b1l + r1)).
// Parity-matched shfl structure; fp8 rows decoded with v_cvt_pk_f32_fp8.
// ---------------------------------------------------------------------------
__global__ __launch_bounds__(256) void gather_ln_relu(
    const int* __restrict__ rowptr, const int* __restrict__ rowdeg,
    const int* __restrict__ adj,
    const unsigned char* __restrict__ feat8, unsigned short* __restrict__ hres,
    const float* __restrict__ b1l, const float* __restrict__ g,
    const float* __restrict__ b) {
  const int lane = threadIdx.x & 63;
  const int wave = threadIdx.x >> 6;
  const int half = lane >> 5;
  const int l5 = lane & 31;
  const int eh = l5 >> 4;
  const int cg = lane & 15;
  const int row = blockIdx.x * 8 + wave * 2 + half;
  const int cgo = cg << 3;

  int e0 = rowptr[row];
  int deg = rowdeg[row];
  float a0 = 0.f, a1 = 0.f, a2 = 0.f, a3 = 0.f;
  float a4 = 0.f, a5 = 0.f, a6 = 0.f, a7 = 0.f;

  for (int be = 0; be < deg; be += 32) {
    int chunk = min(deg - be, 32);
    int ledge = ((l5 & 15) << 1) + eh;     // parity-matched adj assignment
    int my = 0;
    if (ledge < chunk) my = adj[e0 + be + ledge];
#pragma unroll 1
    for (int j = 0; j < chunk; j += 16) {
#pragma unroll
      for (int u = 0; u < 8; ++u) {
        int s = __shfl(my, (half << 5) + (eh << 4) + ((j >> 1) + u));
        if (j + 2 * u + eh < chunk) {
          uint2 v = *(const uint2*)(feat8 + ((size_t)s << 7) + cgo);
          floatx2 p0 = __builtin_amdgcn_cvt_pk_f32_fp8(v.x, false);
          floatx2 p1 = __builtin_amdgcn_cvt_pk_f32_fp8(v.x, true);
          floatx2 p2 = __builtin_amdgcn_cvt_pk_f32_fp8(v.y, false);
          floatx2 p3 = __builtin_amdgcn_cvt_pk_f32_fp8(v.y, true);
          a0 += p0.x; a1 += p0.y; a2 += p1.x; a3 += p1.y;
          a4 += p2.x; a5 += p2.y; a6 += p3.x; a7 += p3.y;
        }
      }
    }
  }
  a0 += __shfl_xor(a0, 16); a1 += __shfl_xor(a1, 16);
  a2 += __shfl_xor(a2, 16); a3 += __shfl_xor(a3, 16);
  a4 += __shfl_xor(a4, 16); a5 += __shfl_xor(a5, 16);
  a6 += __shfl_xor(a6, 16); a7 += __shfl_xor(a7, 16);

  float inv = 1.0f / fmaxf((float)deg, 1.0f);
  size_t base = (size_t)row * 128;
  float4 blo = *(const float4*)(b1l + cgo);
  float4 bhi = *(const float4*)(b1l + cgo + 4);
  uint4 rv = *(const uint4*)(hres + base + cgo);
  float t0 = a0 * inv + blo.x + bf2f_lo(rv.x);
  float t1 = a1 * inv + blo.y + bf2f_hi(rv.x);
  float t2 = a2 * inv + blo.z + bf2f_lo(rv.y);
  float t3 = a3 * inv + blo.w + bf2f_hi(rv.y);
  float t4 = a4 * inv + bhi.x + bf2f_lo(rv.z);
  float t5 = a5 * inv + bhi.y + bf2f_hi(rv.z);
  float t6 = a6 * inv + bhi.z + bf2f_lo(rv.w);
  float t7 = a7 * inv + bhi.w + bf2f_hi(rv.w);

  float s = ((t0 + t1) + (t2 + t3)) + ((t4 + t5) + (t6 + t7));
#pragma unroll
  for (int m = 8; m >= 1; m >>= 1) s += __shfl_xor(s, m);
  float mu = s * (1.0f / 128.0f);
  float d0 = t0 - mu, d1 = t1 - mu, d2 = t2 - mu, d3 = t3 - mu;
  float d4 = t4 - mu, d5 = t5 - mu, d6 = t6 - mu, d7 = t7 - mu;
  float vv = ((d0 * d0 + d1 * d1) + (d2 * d2 + d3 * d3)) +
             ((d4 * d4 + d5 * d5) + (d6 * d6 + d7 * d7));
#pragma unroll
  for (int m = 8; m >= 1; m >>= 1) vv += __shfl_xor(vv, m);
  float rstd = rsqrtf(vv * (1.0f / 128.0f) + 1e-5f);
  if (eh == 0) {
    float4 glo = *(const float4*)(g + cgo);
    float4 ghi = *(const float4*)(g + cgo + 4);
    float4 bl2 = *(const float4*)(b + cgo);
    float4 bh2 = *(const float4*)(b + cgo + 4);
    float h0 = fmaxf(d0 * rstd * glo.x + bl2.x, 0.0f);
    float h1 = fmaxf(d1 * rstd * glo.y + bl2.y, 0.0f);
    float h2 = fmaxf(d2 * rstd * glo.z + bl2.z, 0.0f);
    float h3 = fmaxf(d3 * rstd * glo.w + bl2.w, 0.0f);
    float h4 = fmaxf(d4 * rstd * ghi.x + bh2.x, 0.0f);
    float h5 = fmaxf(d5 * rstd * ghi.y + bh2.y, 0.0f);
    float h6 = fmaxf(d6 * rstd * ghi.z + bh2.z, 0.0f);
    float h7 = fmaxf(d7 * rstd * ghi.w + bh2.w, 0.0f);
    uint4 hv;
    hv.x = (unsigned int)f2bf(h0) | ((unsigned int)f2bf(h1) << 16);
    hv.y = (unsigned int)f2bf(h2) | ((unsigned int)f2bf(h3) << 16);
    hv.z = (unsigned int)f2bf(h4) | ((unsigned int)f2bf(h5) << 16);
    hv.w = (unsigned int)f2bf(h6) | ((unsigned int)f2bf(h7) << 16);
    *(uint4*)(hres + base + cgo) = hv;
  }
}

// ---------------------------------------------------------------------------
// GEMM2: [z2(fp8) | r2(bf16)] = h @ [W2l|W2r] (NCOLS=128). Left half packed
// to fp8 e4m3 through the LDS staging (halves the layer-2 gather's bytes).
// ---------------------------------------------------------------------------
__global__ __launch_bounds__(256) void gemm_mfma2(
    const unsigned short* __restrict__ A, const short* __restrict__ Bswz,
    unsigned char* __restrict__ z8, unsigned short* __restrict__ outR,
    int nrows) {
  constexpr int PW = 32, CT = 2;
  __shared__ char smem[17408];
  auto At = (unsigned short (*)[136])smem;

  const int tid = threadIdx.x;
  const int lane = tid & 63;
  const int wave = tid >> 6;
  const int row0 = blockIdx.x * 64;

  for (int i = tid; i < 64 * 16; i += 256) {
    int r = i >> 4, c8 = (i & 15) << 3;
    int gr = row0 + r;
    uint4 v = make_uint4(0, 0, 0, 0);
    if (gr < nrows) v = *(const uint4*)(A + (size_t)gr * 128 + c8);
    *(uint4*)&At[r][c8] = v;
  }
  __syncthreads();

  short8 bfrag[CT][4];
#pragma unroll
  for (int ct = 0; ct < CT; ++ct)
#pragma unroll
    for (int ks = 0; ks < 4; ++ks)
      bfrag[ct][ks] =
          *(const short8*)(Bswz + ((((wave * CT + ct) * 4 + ks) * 64 + lane) << 3));

  floatx4 acc[4][CT];
#pragma unroll
  for (int rt = 0; rt < 4; ++rt)
#pragma unroll
    for (int ct = 0; ct < CT; ++ct) acc[rt][ct] = (floatx4)(0.f);

#pragma unroll
  for (int rt = 0; rt < 4; ++rt) {
#pragma unroll
    for (int ks = 0; ks < 4; ++ks) {
      short8 af = *(const short8*)&At[rt * 16 + (lane & 15)][ks * 32 + ((lane >> 4) << 3)];
#pragma unroll
      for (int ct = 0; ct < CT; ++ct)
        acc[rt][ct] = __builtin_amdgcn_mfma_f32_16x16x32_bf16(
            bfrag[ct][ks], af, acc[rt][ct], 0, 0, 0);
    }
  }
  __syncthreads();  // A-reads done; reuse smem for C staging

  // Staging: Cs8 = 64 rows x 80B (fp8 z2), Cs16 = 64 rows x 72 ushorts (r2).
  unsigned char* Cs8 = (unsigned char*)smem;
  unsigned short* Cs16 = (unsigned short*)(smem + 64 * 80);

#pragma unroll
  for (int rt = 0; rt < 4; ++rt) {
    int rl = rt * 16 + (lane & 15);
#pragma unroll
    for (int ct = 0; ct < CT; ++ct) {
      int c = wave * PW + ct * 16 + ((lane >> 4) << 2);
      floatx4 a = acc[rt][ct];
      if (c < 64) {  // wave-uniform (waves 0-1)
        int pk = __builtin_amdgcn_cvt_pk_fp8_f32(a[0], a[1], 0, false);
        pk = __builtin_amdgcn_cvt_pk_fp8_f32(a[2], a[3], pk, true);
        *(unsigned int*)(Cs8 + rl * 80 + c) = (unsigned int)pk;
      } else {
        ushort4 u = make_ushort4(f2bf(a[0]), f2bf(a[1]), f2bf(a[2]), f2bf(a[3]));
        *(ushort4*)(Cs16 + rl * 72 + (c - 64)) = u;
      }
    }
  }
  __syncthreads();
  // z2 fp8 writeback: 64 rows x 4 uint4 chunks = 256 (1/thread).
  {
    int rl = tid >> 2, cpos = (tid & 3) << 4;
    int gr = row0 + rl;
    if (gr < nrows) {
      uint4 v = *(const uint4*)(Cs8 + rl * 80 + cpos);
      *(uint4*)(z8 + (size_t)gr * 64 + cpos) = v;
    }
  }
  // r2 bf16 writeback: 64 rows x 8 uint4 chunks = 512 (2/thread).
  for (int i = tid; i < 512; i += 256) {
    int rl = i >> 3, cpos = (i & 7) << 3;
    int gr = row0 + rl;
    if (gr < nrows) {
      uint4 v = *(const uint4*)(Cs16 + rl * 72 + cpos);
      *(uint4*)(outR + (size_t)gr * 64 + cpos) = v;
    }
  }
}

// ---------------------------------------------------------------------------
// Layer-2 gather + epilogue: out = l2norm(mean_agg(z2_fp8) + b2l + r2), fp32.
// ---------------------------------------------------------------------------
__global__ __launch_bounds__(256) void gather_l2norm(
    const int* __restrict__ rowptr, const int* __restrict__ rowdeg,
    const int* __restrict__ adj,
    const unsigned char* __restrict__ z8, const unsigned short* __restrict__ r2,
    const float* __restrict__ b2l, float* __restrict__ out) {
  const int lane = threadIdx.x & 63;
  const int wave = threadIdx.x >> 6;
  const int half = lane >> 5;
  const int l5 = lane & 31;
  const int eh = l5 >> 4;
  const int cg = lane & 15;
  const int row = blockIdx.x * 8 + wave * 2 + half;

  int e0 = rowptr[row];
  int deg = rowdeg[row];
  float a0 = 0.f, a1 = 0.f, a2 = 0.f, a3 = 0.f;

  for (int be = 0; be < deg; be += 32) {
    int chunk = min(deg - be, 32);
    int ledge = ((l5 & 15) << 1) + eh;
    int my = 0;
    if (ledge < chunk) my = adj[e0 + be + ledge];
#pragma unroll 1
    for (int j = 0; j < chunk; j += 16) {
#pragma unroll
      for (int u = 0; u < 8; ++u) {
        int s = __shfl(my, (half << 5) + (eh << 4) + ((j >> 1) + u));
        if (j + 2 * u + eh < chunk) {
          unsigned int v = *(const unsigned int*)(z8 + ((size_t)s << 6) + (cg << 2));
          floatx2 p0 = __builtin_amdgcn_cvt_pk_f32_fp8(v, false);
          floatx2 p1 = __builtin_amdgcn_cvt_pk_f32_fp8(v, true);
          a0 += p0.x; a1 += p0.y; a2 += p1.x; a3 += p1.y;
        }
      }
    }
  }
  a0 += __shfl_xor(a0, 16); a1 += __shfl_xor(a1, 16);
  a2 += __shfl_xor(a2, 16); a3 += __shfl_xor(a3, 16);

  float inv = 1.0f / fmaxf((float)deg, 1.0f);
  int c0 = cg << 2;
  size_t base = (size_t)row * 64;
  float4 bias = *(const float4*)(b2l + c0);
  uint2 rv = *(const uint2*)(r2 + base + c0);
  float t0 = a0 * inv + bias.x + bf2f_lo(rv.x);
  float t1 = a1 * inv + bias.y + bf2f_hi(rv.x);
  float t2 = a2 * inv + bias.z + bf2f_lo(rv.y);
  float t3 = a3 * inv + bias.w + bf2f_hi(rv.y);
  float s = (t0 * t0 + t1 * t1) + (t2 * t2 + t3 * t3);
#pragma unroll
  for (int m = 8; m >= 1; m >>= 1) s += __shfl_xor(s, m);
  float nrm = fmaxf(sqrtf(s), 1e-12f);
  if (eh == 0) {
    float4 o;
    o.x = t0 / nrm; o.y = t1 / nrm; o.z = t2 / nrm; o.w = t3 / nrm;
    *(float4*)(out + base + c0) = o;
  }
}

extern "C" void kernel_launch(void* const* d_in, const int* in_sizes, int n_in,
                              void* d_out, int out_size, void* d_ws, size_t ws_size,
                              hipStream_t stream) {
  const float* x   = (const float*)d_in[0];
  const int*   ei  = (const int*)d_in[1];
  const float* W1l = (const float*)d_in[2];
  const float* b1l = (const float*)d_in[3];
  const float* W1r = (const float*)d_in[4];
  const float* lng = (const float*)d_in[5];
  const float* lnb = (const float*)d_in[6];
  const float* W2l = (const float*)d_in[7];
  const float* b2l = (const float*)d_in[8];
  const float* W2r = (const float*)d_in[9];
  float* out = (float*)d_out;

  const int N = NNODES;

  unsigned char*  y8  = (unsigned char*)d_ws;                     // N*128 fp8
  unsigned short* r1b = (unsigned short*)(y8 + (size_t)N * 128);  // N*128 bf16
  unsigned char*  z8  = (unsigned char*)(r1b + (size_t)N * 128);  // N*64 fp8
  unsigned short* r2b = (unsigned short*)(z8 + (size_t)N * 64);   // N*64 bf16
  short* bswz1 = (short*)(r2b + (size_t)N * 64);                  // 32768
  short* bswz2 = bswz1 + 32768;                                   // 16384
  int* rowptr = (int*)(bswz2 + 16384);                            // N
  int* rowdeg = rowptr + N;                                       // N
  int* adj    = rowdeg + N;                                       // NBUCK*BCAP
  unsigned int* part = (unsigned int*)(adj + NBUCK * BCAP);       // NBUCK*BCAP
  int* bcur  = (int*)(part + NBUCK * BCAP);                       // NBUCK

  // front1 = prep_b(W1) || prep_b(W2) || bcur init (fixed bucket bases)
  front1<<<193, 256, 0, stream>>>(W1l, W1r, bswz1, W2l, W2r, bswz2, bcur);
  // front2 = bucket_partition (first) || GEMM1 ([y1(fp8)|r1] = x @ [W1l|W1r])
  front2<<<GEMM_BLOCKS + NBLK_A, 512, 0, stream>>>(x, bswz1, y8, r1b, ei,
                                                   bcur, part);
  bucket_build<<<NBUCK, 256, 0, stream>>>(part, bcur, rowptr, rowdeg, adj);

  const int gat_blocks = N / 8;  // 12500

  // Layer 1 epilogue: pull-aggregate y1(fp8); fused mean+bias+res+LN+ReLU.
  gather_ln_relu<<<gat_blocks, 256, 0, stream>>>(rowptr, rowdeg, adj, y8, r1b,
                                                 b1l, lng, lnb);

  // Layer 2: [z2(fp8) | r2] = h @ [W2l|W2r]; pull-aggregate z2; fused
  // mean+bias+residual+L2norm -> out (fp32).
  gemm_mfma2<<<GEMM_BLOCKS, 256, 0, stream>>>(r1b, bswz2, z8, r2b, N);
  gather_l2norm<<<gat_blocks, 256, 0, stream>>>(rowptr, rowdeg, adj, z8, r2b,
                                                b2l, out);
}

// Round 18
// 170.075 us; speedup vs baseline: 1.0073x; 1.0073x over previous
//
#include <hip/hip_runtime.h>
#include <hip/hip_bf16.h>

#define NNODES 100000
#define NEDGES 1600000
#define NBUCK 391        // ceil(NNODES / 256), 256 nodes per bucket
#define BUCK_SHIFT 8
#define BCAP 5120        // fixed bucket capacity (mean 4092, +16 sigma)
#define NBLK_A 782       // ceil(NEDGES / 2048)
#define GEMM_BLOCKS 1563 // ceil(NNODES / 64)

typedef short short8 __attribute__((ext_vector_type(8)));
typedef float floatx4 __attribute__((ext_vector_type(4)));
typedef float floatx2 __attribute__((ext_vector_type(2)));

__device__ inline float bf2f_lo(unsigned int v) {
  union { unsigned int i; float f; } u; u.i = v << 16; return u.f;
}
__device__ inline float bf2f_hi(unsigned int v) {
  union { unsigned int i; float f; } u; u.i = v & 0xffff0000u; return u.f;
}
__device__ inline unsigned short f2bf(float f) {  // RNE
  union { float f; unsigned int i; } u; u.f = f;
  unsigned int r = u.i + 0x7fffu + ((u.i >> 16) & 1u);
  return (unsigned short)(r >> 16);
}

// ---------------------------------------------------------------------------
// Weight prep body: Bcat = [Wl | Wr] (128 x 2*half) -> bf16 fragment-
// contiguous layout for the GEMM's B-panel register loads.
// ---------------------------------------------------------------------------
__device__ void prep_body(int bid, int nblk, const float* __restrict__ Wl,
                          const float* __restrict__ Wr,
                          short* __restrict__ Bswz, int half) {
  int total = 128 * 2 * half;
  int stride = nblk * 256;
  for (int i = bid * 256 + threadIdx.x; i < total; i += stride) {
    int j = i & 7;
    int lane = (i >> 3) & 63;
    int f = i >> 9;  // frag id = ct*4 + ks
    int ks = f & 3, ct = f >> 2;
    int k = ks * 32 + ((lane >> 4) << 3) + j;
    int c = ct * 16 + (lane & 15);
    float v = (c < half) ? Wl[k * half + c] : Wr[k * half + (c - half)];
    Bswz[i] = (short)f2bf(v);
  }
}

// ---------------------------------------------------------------------------
// GEMM1 body (512 threads / 8 waves): [y1(fp8)|r1(bf16)] = x(fp32)@[W1l|W1r].
// LDS A staging, CT=2 (32 AGPRs/wave -> ~51% occupancy).
// ---------------------------------------------------------------------------
__device__ void gemm1_body(int bid, const float* __restrict__ A,
                           const short* __restrict__ Bswz,
                           unsigned char* __restrict__ y8,
                           unsigned short* __restrict__ r1, int nrows,
                           char* smem) {
  constexpr int PW = 32, CT = 2;
  auto At = (unsigned short (*)[136])smem;

  const int tid = threadIdx.x;
  const int lane = tid & 63;
  const int wave = tid >> 6;  // 0..7
  const int row0 = bid * 64;

  for (int i = tid; i < 64 * 32; i += 512) {
    int r = i >> 5, c4 = (i & 31) << 2;
    int gr = row0 + r;
    float4 v = make_float4(0.f, 0.f, 0.f, 0.f);
    if (gr < nrows) v = *(const float4*)(A + (size_t)gr * 128 + c4);
    ushort4 u = make_ushort4(f2bf(v.x), f2bf(v.y), f2bf(v.z), f2bf(v.w));
    *(ushort4*)&At[r][c4] = u;
  }
  __syncthreads();

  short8 bfrag[CT][4];
#pragma unroll
  for (int ct = 0; ct < CT; ++ct)
#pragma unroll
    for (int ks = 0; ks < 4; ++ks)
      bfrag[ct][ks] =
          *(const short8*)(Bswz + ((((wave * CT + ct) * 4 + ks) * 64 + lane) << 3));

  floatx4 acc[4][CT];
#pragma unroll
  for (int rt = 0; rt < 4; ++rt)
#pragma unroll
    for (int ct = 0; ct < CT; ++ct) acc[rt][ct] = (floatx4)(0.f);

#pragma unroll
  for (int rt = 0; rt < 4; ++rt) {
#pragma unroll
    for (int ks = 0; ks < 4; ++ks) {
      short8 af = *(const short8*)&At[rt * 16 + (lane & 15)][ks * 32 + ((lane >> 4) << 3)];
#pragma unroll
      for (int ct = 0; ct < CT; ++ct)
        acc[rt][ct] = __builtin_amdgcn_mfma_f32_16x16x32_bf16(
            bfrag[ct][ks], af, acc[rt][ct], 0, 0, 0);
    }
  }
  __syncthreads();  // A-reads done; reuse smem for C staging

  // Staging: Cs8 = 32 rows x 144B (fp8), Cs16 = 32 rows x 136 ushorts.
  unsigned char* Cs8 = (unsigned char*)smem;
  unsigned short* Cs16 = (unsigned short*)(smem + 32 * 144);

#pragma unroll
  for (int p = 0; p < 2; ++p) {  // 2 passes of 32 rows
    if (p) __syncthreads();
#pragma unroll
    for (int rr = 0; rr < 2; ++rr) {
      int rt = p * 2 + rr;
      int rl = rr * 16 + (lane & 15);
#pragma unroll
      for (int ct = 0; ct < CT; ++ct) {
        int c = wave * PW + ct * 16 + ((lane >> 4) << 2);
        floatx4 a = acc[rt][ct];
        if (c < 128) {  // wave-uniform (waves 0-3)
          int pk = __builtin_amdgcn_cvt_pk_fp8_f32(a[0], a[1], 0, false);
          pk = __builtin_amdgcn_cvt_pk_fp8_f32(a[2], a[3], pk, true);
          *(unsigned int*)(Cs8 + rl * 144 + c) = (unsigned int)pk;
        } else {
          ushort4 u = make_ushort4(f2bf(a[0]), f2bf(a[1]), f2bf(a[2]), f2bf(a[3]));
          *(ushort4*)(Cs16 + rl * 136 + (c - 128)) = u;
        }
      }
    }
    __syncthreads();
    // y1 fp8 writeback: 32 rows x 8 uint4 chunks = 256.
    if (tid < 256) {
      int rl = tid >> 3, cpos = (tid & 7) << 4;
      int gr = row0 + p * 32 + rl;
      if (gr < nrows) {
        uint4 v = *(const uint4*)(Cs8 + rl * 144 + cpos);
        *(uint4*)(y8 + (size_t)gr * 128 + cpos) = v;
      }
    }
    // r1 bf16 writeback: 32 rows x 16 uint4 chunks = 512 (1/thread).
    {
      int rl = tid >> 4, cpos = (tid & 15) << 3;
      int gr = row0 + p * 32 + rl;
      if (gr < nrows) {
        uint4 v = *(const uint4*)(Cs16 + rl * 136 + cpos);
        *(uint4*)(r1 + (size_t)gr * 128 + cpos) = v;
      }
    }
  }
}

// ---------------------------------------------------------------------------
// CSR build: fixed-capacity buckets (base = b*BCAP) — no count/scan kernels.
// ---------------------------------------------------------------------------
__device__ void partition_body(int bid, const int* __restrict__ ei,
                               int* __restrict__ bcur,
                               unsigned int* __restrict__ part, char* smem) {
  int* h = (int*)smem;          // NBUCK
  int* r = h + NBUCK;           // NBUCK
  for (int i = threadIdx.x; i < NBUCK; i += blockDim.x) { h[i] = 0; r[i] = 0; }
  __syncthreads();
  int e0 = bid * 2048;
  int eend = min(e0 + 2048, NEDGES);
  for (int e = e0 + threadIdx.x; e < eend; e += blockDim.x)
    atomicAdd(&h[ei[NEDGES + e] >> BUCK_SHIFT], 1);
  __syncthreads();
  for (int i = threadIdx.x; i < NBUCK; i += blockDim.x) {
    int c = h[i];
    h[i] = c ? atomicAdd(&bcur[i], c) : 0;  // reserve chunk
  }
  __syncthreads();
  for (int e = e0 + threadIdx.x; e < eend; e += blockDim.x) {
    int s = ei[e], d = ei[NEDGES + e];
    int b = d >> BUCK_SHIFT;
    int pos = h[b] + atomicAdd(&r[b], 1);
    if (pos < (b + 1) * BCAP)  // overflow guard (never fires: cap = +16 sigma)
      part[pos] = (unsigned int)s | ((unsigned int)(d & 255) << 24);
  }
}

// front1 = prep_b W1 (128) || prep_b W2 (64) || bcur init (1)
__global__ __launch_bounds__(256) void front1(
    const float* __restrict__ W1l, const float* __restrict__ W1r,
    short* __restrict__ bswz1, const float* __restrict__ W2l,
    const float* __restrict__ W2r, short* __restrict__ bswz2,
    int* __restrict__ bcur) {
  int bid = blockIdx.x;
  if (bid < 128) {
    prep_body(bid, 128, W1l, W1r, bswz1, 128);
  } else if (bid < 192) {
    prep_body(bid - 128, 64, W2l, W2r, bswz2, 64);
  } else {
    for (int i = threadIdx.x; i < NBUCK; i += 256) bcur[i] = i * BCAP;
  }
}

// front2 = GEMM1 (1563) || bucket_partition (782), 512 threads, LDS overlaid.
__global__ __launch_bounds__(512) void front2(
    const float* __restrict__ x, const short* __restrict__ bswz1,
    unsigned char* __restrict__ y8, unsigned short* __restrict__ r1b,
    const int* __restrict__ ei, int* __restrict__ bcur,
    unsigned int* __restrict__ part) {
  __shared__ char smem[17408];
  int bid = blockIdx.x;
  if (bid < GEMM_BLOCKS) {
    gemm1_body(bid, x, bswz1, y8, r1b, NNODES, smem);
  } else {
    partition_body(bid - GEMM_BLOCKS, ei, bcur, part, smem);
  }
}

// Per bucket: local 256-node hist -> rowptr (absolute) + rowdeg; place srcs
// into adj (writes confined to the bucket's own fixed region).
__global__ __launch_bounds__(256) void bucket_build(
    const unsigned int* __restrict__ part, const int* __restrict__ bcur,
    int* __restrict__ rowptr, int* __restrict__ rowdeg,
    int* __restrict__ adj) {
  __shared__ int h[256], ex[256];
  int b = blockIdx.x;
  int t = threadIdx.x;
  int base = b * BCAP;
  int cnt = min(bcur[b] - base, BCAP);
  int end = base + cnt;
  h[t] = 0;
  __syncthreads();
  for (int i = base + t; i < end; i += 256)
    atomicAdd(&h[part[i] >> 24], 1);
  __syncthreads();
  int v = h[t];
  int acc = v;
  ex[t] = acc;
  __syncthreads();
  for (int off = 1; off < 256; off <<= 1) {
    int add = (t >= off) ? ex[t - off] : 0;
    __syncthreads();
    acc += add;
    ex[t] = acc;
    __syncthreads();
  }
  int excl = acc - v;
  int node = (b << BUCK_SHIFT) + t;
  if (node < NNODES) {
    rowptr[node] = base + excl;
    rowdeg[node] = v;
  }
  h[t] = 0;
  ex[t] = excl;
  __syncthreads();
  for (int i = base + t; i < end; i += 256) {
    unsigned int p = part[i];
    int ld = p >> 24;
    int rank = atomicAdd(&h[ld], 1);
    adj[base + ex[ld] + rank] = (int)(p & 0xFFFFFFu);
  }
}

// ---------------------------------------------------------------------------
// Layer-1 gather + epilogue: h = relu(LN(mean_agg(y1_fp8) + b1l + r1)).
// Parity-matched shfl structure; fp8 rows decoded with v_cvt_pk_f32_fp8.
// ---------------------------------------------------------------------------
__global__ __launch_bounds__(256) void gather_ln_relu(
    const int* __restrict__ rowptr, const int* __restrict__ rowdeg,
    const int* __restrict__ adj,
    const unsigned char* __restrict__ feat8, unsigned short* __restrict__ hres,
    const float* __restrict__ b1l, const float* __restrict__ g,
    const float* __restrict__ b) {
  const int lane = threadIdx.x & 63;
  const int wave = threadIdx.x >> 6;
  const int half = lane >> 5;
  const int l5 = lane & 31;
  const int eh = l5 >> 4;
  const int cg = lane & 15;
  const int row = blockIdx.x * 8 + wave * 2 + half;
  const int cgo = cg << 3;

  int e0 = rowptr[row];
  int deg = rowdeg[row];
  float a0 = 0.f, a1 = 0.f, a2 = 0.f, a3 = 0.f;
  float a4 = 0.f, a5 = 0.f, a6 = 0.f, a7 = 0.f;

  for (int be = 0; be < deg; be += 32) {
    int chunk = min(deg - be, 32);
    int ledge = ((l5 & 15) << 1) + eh;     // parity-matched adj assignment
    int my = 0;
    if (ledge < chunk) my = adj[e0 + be + ledge];
#pragma unroll 1
    for (int j = 0; j < chunk; j += 16) {
#pragma unroll
      for (int u = 0; u < 8; ++u) {
        int s = __shfl(my, (half << 5) + (eh << 4) + ((j >> 1) + u));
        if (j + 2 * u + eh < chunk) {
          uint2 v = *(const uint2*)(feat8 + ((size_t)s << 7) + cgo);
          floatx2 p0 = __builtin_amdgcn_cvt_pk_f32_fp8(v.x, false);
          floatx2 p1 = __builtin_amdgcn_cvt_pk_f32_fp8(v.x, true);
          floatx2 p2 = __builtin_amdgcn_cvt_pk_f32_fp8(v.y, false);
          floatx2 p3 = __builtin_amdgcn_cvt_pk_f32_fp8(v.y, true);
          a0 += p0.x; a1 += p0.y; a2 += p1.x; a3 += p1.y;
          a4 += p2.x; a5 += p2.y; a6 += p3.x; a7 += p3.y;
        }
      }
    }
  }
  a0 += __shfl_xor(a0, 16); a1 += __shfl_xor(a1, 16);
  a2 += __shfl_xor(a2, 16); a3 += __shfl_xor(a3, 16);
  a4 += __shfl_xor(a4, 16); a5 += __shfl_xor(a5, 16);
  a6 += __shfl_xor(a6, 16); a7 += __shfl_xor(a7, 16);

  float inv = 1.0f / fmaxf((float)deg, 1.0f);
  size_t base = (size_t)row * 128;
  float4 blo = *(const float4*)(b1l + cgo);
  float4 bhi = *(const float4*)(b1l + cgo + 4);
  uint4 rv = *(const uint4*)(hres + base + cgo);
  float t0 = a0 * inv + blo.x + bf2f_lo(rv.x);
  float t1 = a1 * inv + blo.y + bf2f_hi(rv.x);
  float t2 = a2 * inv + blo.z + bf2f_lo(rv.y);
  float t3 = a3 * inv + blo.w + bf2f_hi(rv.y);
  float t4 = a4 * inv + bhi.x + bf2f_lo(rv.z);
  float t5 = a5 * inv + bhi.y + bf2f_hi(rv.z);
  float t6 = a6 * inv + bhi.z + bf2f_lo(rv.w);
  float t7 = a7 * inv + bhi.w + bf2f_hi(rv.w);

  float s = ((t0 + t1) + (t2 + t3)) + ((t4 + t5) + (t6 + t7));
#pragma unroll
  for (int m = 8; m >= 1; m >>= 1) s += __shfl_xor(s, m);
  float mu = s * (1.0f / 128.0f);
  float d0 = t0 - mu, d1 = t1 - mu, d2 = t2 - mu, d3 = t3 - mu;
  float d4 = t4 - mu, d5 = t5 - mu, d6 = t6 - mu, d7 = t7 - mu;
  float vv = ((d0 * d0 + d1 * d1) + (d2 * d2 + d3 * d3)) +
             ((d4 * d4 + d5 * d5) + (d6 * d6 + d7 * d7));
#pragma unroll
  for (int m = 8; m >= 1; m >>= 1) vv += __shfl_xor(vv, m);
  float rstd = rsqrtf(vv * (1.0f / 128.0f) + 1e-5f);
  if (eh == 0) {
    float4 glo = *(const float4*)(g + cgo);
    float4 ghi = *(const float4*)(g + cgo + 4);
    float4 bl2 = *(const float4*)(b + cgo);
    float4 bh2 = *(const float4*)(b + cgo + 4);
    float h0 = fmaxf(d0 * rstd * glo.x + bl2.x, 0.0f);
    float h1 = fmaxf(d1 * rstd * glo.y + bl2.y, 0.0f);
    float h2 = fmaxf(d2 * rstd * glo.z + bl2.z, 0.0f);
    float h3 = fmaxf(d3 * rstd * glo.w + bl2.w, 0.0f);
    float h4 = fmaxf(d4 * rstd * ghi.x + bh2.x, 0.0f);
    float h5 = fmaxf(d5 * rstd * ghi.y + bh2.y, 0.0f);
    float h6 = fmaxf(d6 * rstd * ghi.z + bh2.z, 0.0f);
    float h7 = fmaxf(d7 * rstd * ghi.w + bh2.w, 0.0f);
    uint4 hv;
    hv.x = (unsigned int)f2bf(h0) | ((unsigned int)f2bf(h1) << 16);
    hv.y = (unsigned int)f2bf(h2) | ((unsigned int)f2bf(h3) << 16);
    hv.z = (unsigned int)f2bf(h4) | ((unsigned int)f2bf(h5) << 16);
    hv.w = (unsigned int)f2bf(h6) | ((unsigned int)f2bf(h7) << 16);
    *(uint4*)(hres + base + cgo) = hv;
  }
}

// ---------------------------------------------------------------------------
// GEMM2: [z2(fp8) | r2(bf16)] = h @ [W2l|W2r] (NCOLS=128). Left half packed
// to fp8 e4m3 through the LDS staging (halves the layer-2 gather's bytes).
// ---------------------------------------------------------------------------
__global__ __launch_bounds__(256) void gemm_mfma2(
    const unsigned short* __restrict__ A, const short* __restrict__ Bswz,
    unsigned char* __restrict__ z8, unsigned short* __restrict__ outR,
    int nrows) {
  constexpr int PW = 32, CT = 2;
  __shared__ char smem[17408];
  auto At = (unsigned short (*)[136])smem;

  const int tid = threadIdx.x;
  const int lane = tid & 63;
  const int wave = tid >> 6;
  const int row0 = blockIdx.x * 64;

  for (int i = tid; i < 64 * 16; i += 256) {
    int r = i >> 4, c8 = (i & 15) << 3;
    int gr = row0 + r;
    uint4 v = make_uint4(0, 0, 0, 0);
    if (gr < nrows) v = *(const uint4*)(A + (size_t)gr * 128 + c8);
    *(uint4*)&At[r][c8] = v;
  }
  __syncthreads();

  short8 bfrag[CT][4];
#pragma unroll
  for (int ct = 0; ct < CT; ++ct)
#pragma unroll
    for (int ks = 0; ks < 4; ++ks)
      bfrag[ct][ks] =
          *(const short8*)(Bswz + ((((wave * CT + ct) * 4 + ks) * 64 + lane) << 3));

  floatx4 acc[4][CT];
#pragma unroll
  for (int rt = 0; rt < 4; ++rt)
#pragma unroll
    for (int ct = 0; ct < CT; ++ct) acc[rt][ct] = (floatx4)(0.f);

#pragma unroll
  for (int rt = 0; rt < 4; ++rt) {
#pragma unroll
    for (int ks = 0; ks < 4; ++ks) {
      short8 af = *(const short8*)&At[rt * 16 + (lane & 15)][ks * 32 + ((lane >> 4) << 3)];
#pragma unroll
      for (int ct = 0; ct < CT; ++ct)
        acc[rt][ct] = __builtin_amdgcn_mfma_f32_16x16x32_bf16(
            bfrag[ct][ks], af, acc[rt][ct], 0, 0, 0);
    }
  }
  __syncthreads();  // A-reads done; reuse smem for C staging

  // Staging: Cs8 = 64 rows x 80B (fp8 z2), Cs16 = 64 rows x 72 ushorts (r2).
  unsigned char* Cs8 = (unsigned char*)smem;
  unsigned short* Cs16 = (unsigned short*)(smem + 64 * 80);

#pragma unroll
  for (int rt = 0; rt < 4; ++rt) {
    int rl = rt * 16 + (lane & 15);
#pragma unroll
    for (int ct = 0; ct < CT; ++ct) {
      int c = wave * PW + ct * 16 + ((lane >> 4) << 2);
      floatx4 a = acc[rt][ct];
      if (c < 64) {  // wave-uniform (waves 0-1)
        int pk = __builtin_amdgcn_cvt_pk_fp8_f32(a[0], a[1], 0, false);
        pk = __builtin_amdgcn_cvt_pk_fp8_f32(a[2], a[3], pk, true);
        *(unsigned int*)(Cs8 + rl * 80 + c) = (unsigned int)pk;
      } else {
        ushort4 u = make_ushort4(f2bf(a[0]), f2bf(a[1]), f2bf(a[2]), f2bf(a[3]));
        *(ushort4*)(Cs16 + rl * 72 + (c - 64)) = u;
      }
    }
  }
  __syncthreads();
  // z2 fp8 writeback: 64 rows x 4 uint4 chunks = 256 (1/thread).
  {
    int rl = tid >> 2, cpos = (tid & 3) << 4;
    int gr = row0 + rl;
    if (gr < nrows) {
      uint4 v = *(const uint4*)(Cs8 + rl * 80 + cpos);
      *(uint4*)(z8 + (size_t)gr * 64 + cpos) = v;
    }
  }
  // r2 bf16 writeback: 64 rows x 8 uint4 chunks = 512 (2/thread).
  for (int i = tid; i < 512; i += 256) {
    int rl = i >> 3, cpos = (i & 7) << 3;
    int gr = row0 + rl;
    if (gr < nrows) {
      uint4 v = *(const uint4*)(Cs16 + rl * 72 + cpos);
      *(uint4*)(outR + (size_t)gr * 64 + cpos) = v;
    }
  }
}

// ---------------------------------------------------------------------------
// Layer-2 gather + epilogue: out = l2norm(mean_agg(z2_fp8) + b2l + r2), fp32.
// ---------------------------------------------------------------------------
__global__ __launch_bounds__(256) void gather_l2norm(
    const int* __restrict__ rowptr, const int* __restrict__ rowdeg,
    const int* __restrict__ adj,
    const unsigned char* __restrict__ z8, const unsigned short* __restrict__ r2,
    const float* __restrict__ b2l, float* __restrict__ out) {
  const int lane = threadIdx.x & 63;
  const int wave = threadIdx.x >> 6;
  const int half = lane >> 5;
  const int l5 = lane & 31;
  const int eh = l5 >> 4;
  const int cg = lane & 15;
  const int row = blockIdx.x * 8 + wave * 2 + half;

  int e0 = rowptr[row];
  int deg = rowdeg[row];
  float a0 = 0.f, a1 = 0.f, a2 = 0.f, a3 = 0.f;

  for (int be = 0; be < deg; be += 32) {
    int chunk = min(deg - be, 32);
    int ledge = ((l5 & 15) << 1) + eh;
    int my = 0;
    if (ledge < chunk) my = adj[e0 + be + ledge];
#pragma unroll 1
    for (int j = 0; j < chunk; j += 16) {
#pragma unroll
      for (int u = 0; u < 8; ++u) {
        int s = __shfl(my, (half << 5) + (eh << 4) + ((j >> 1) + u));
        if (j + 2 * u + eh < chunk) {
          unsigned int v = *(const unsigned int*)(z8 + ((size_t)s << 6) + (cg << 2));
          floatx2 p0 = __builtin_amdgcn_cvt_pk_f32_fp8(v, false);
          floatx2 p1 = __builtin_amdgcn_cvt_pk_f32_fp8(v, true);
          a0 += p0.x; a1 += p0.y; a2 += p1.x; a3 += p1.y;
        }
      }
    }
  }
  a0 += __shfl_xor(a0, 16); a1 += __shfl_xor(a1, 16);
  a2 += __shfl_xor(a2, 16); a3 += __shfl_xor(a3, 16);

  float inv = 1.0f / fmaxf((float)deg, 1.0f);
  int c0 = cg << 2;
  size_t base = (size_t)row * 64;
  float4 bias = *(const float4*)(b2l + c0);
  uint2 rv = *(const uint2*)(r2 + base + c0);
  float t0 = a0 * inv + bias.x + bf2f_lo(rv.x);
  float t1 = a1 * inv + bias.y + bf2f_hi(rv.x);
  float t2 = a2 * inv + bias.z + bf2f_lo(rv.y);
  float t3 = a3 * inv + bias.w + bf2f_hi(rv.y);
  float s = (t0 * t0 + t1 * t1) + (t2 * t2 + t3 * t3);
#pragma unroll
  for (int m = 8; m >= 1; m >>= 1) s += __shfl_xor(s, m);
  float nrm = fmaxf(sqrtf(s), 1e-12f);
  if (eh == 0) {
    float4 o;
    o.x = t0 / nrm; o.y = t1 / nrm; o.z = t2 / nrm; o.w = t3 / nrm;
    *(float4*)(out + base + c0) = o;
  }
}

extern "C" void kernel_launch(void* const* d_in, const int* in_sizes, int n_in,
                              void* d_out, int out_size, void* d_ws, size_t ws_size,
                              hipStream_t stream) {
  const float* x   = (const float*)d_in[0];
  const int*   ei  = (const int*)d_in[1];
  const float* W1l = (const float*)d_in[2];
  const float* b1l = (const float*)d_in[3];
  const float* W1r = (const float*)d_in[4];
  const float* lng = (const float*)d_in[5];
  const float* lnb = (const float*)d_in[6];
  const float* W2l = (const float*)d_in[7];
  const float* b2l = (const float*)d_in[8];
  const float* W2r = (const float*)d_in[9];
  float* out = (float*)d_out;

  const int N = NNODES;

  unsigned char*  y8  = (unsigned char*)d_ws;                     // N*128 fp8
  unsigned short* r1b = (unsigned short*)(y8 + (size_t)N * 128);  // N*128 bf16
  unsigned char*  z8  = (unsigned char*)(r1b + (size_t)N * 128);  // N*64 fp8
  unsigned short* r2b = (unsigned short*)(z8 + (size_t)N * 64);   // N*64 bf16
  short* bswz1 = (short*)(r2b + (size_t)N * 64);                  // 32768
  short* bswz2 = bswz1 + 32768;                                   // 16384
  int* rowptr = (int*)(bswz2 + 16384);                            // N
  int* rowdeg = rowptr + N;                                       // N
  int* adj    = rowdeg + N;                                       // NBUCK*BCAP
  unsigned int* part = (unsigned int*)(adj + NBUCK * BCAP);       // NBUCK*BCAP
  int* bcur  = (int*)(part + NBUCK * BCAP);                       // NBUCK

  // front1 = prep_b(W1) || prep_b(W2) || bcur init (fixed bucket bases)
  front1<<<193, 256, 0, stream>>>(W1l, W1r, bswz1, W2l, W2r, bswz2, bcur);
  // front2 = GEMM1 ([y1(fp8)|r1] = x @ [W1l|W1r]) || bucket_partition
  front2<<<GEMM_BLOCKS + NBLK_A, 512, 0, stream>>>(x, bswz1, y8, r1b, ei,
                                                   bcur, part);
  bucket_build<<<NBUCK, 256, 0, stream>>>(part, bcur, rowptr, rowdeg, adj);

  const int gat_blocks = N / 8;  // 12500

  // Layer 1 epilogue: pull-aggregate y1(fp8); fused mean+bias+res+LN+ReLU.
  gather_ln_relu<<<gat_blocks, 256, 0, stream>>>(rowptr, rowdeg, adj, y8, r1b,
                                                 b1l, lng, lnb);

  // Layer 2: [z2(fp8) | r2] = h @ [W2l|W2r]; pull-aggregate z2; fused
  // mean+bias+residual+L2norm -> out (fp32).
  gemm_mfma2<<<GEMM_BLOCKS, 256, 0, stream>>>(r1b, bswz2, z8, r2b, N);
  gather_l2norm<<<gat_blocks, 256, 0, stream>>>(rowptr, rowdeg, adj, z8, r2b,
                                                b2l, out);
}